// Round 6
// baseline (194.642 us; speedup 1.0000x reference)
//
#include <hip/hip_runtime.h>
#include <cstdint>
#include <cstddef>

#define NNODES 100000
#define FEATD  256
#define HIDD   256
#define NBATCH 512
#define FAN1   10            // hop-1 fanout
#define FAN2   25            // hop-2 fanout
#define NS1    (NBATCH*FAN1) // 5120
#define MTOT   (NBATCH+NS1)  // 5632

typedef __attribute__((ext_vector_type(8))) short short8;
typedef __attribute__((ext_vector_type(4))) float f32x4;

__device__ __forceinline__ unsigned short f2bf(float f) {
    unsigned int u = __float_as_uint(f);
    unsigned int r = (u + 0x7fffu + ((u >> 16) & 1u)) >> 16;
    return (unsigned short)r;
}
__device__ __forceinline__ float bf2f(unsigned short h) {
    return __uint_as_float(((unsigned int)h) << 16);
}

// ---------------- kernel 1: W convert + transpose (both layers) ----------------
__global__ __launch_bounds__(256) void k_wcvt(
    const float* __restrict__ Ws0, const float* __restrict__ Wn0,
    const float* __restrict__ Ws1, const float* __restrict__ Wn1,
    unsigned short* __restrict__ B0t, unsigned short* __restrict__ B1t) {
    __shared__ unsigned short Ts[64][72];
    const int t     = threadIdx.x;
    const int which = blockIdx.x >> 5;
    const int loc   = blockIdx.x & 31;
    const int kt = loc >> 2, nt = loc & 3;
    const int k0 = kt * 64, n0 = nt * 64;
    const float* W;
    if (which == 0)
        W = (k0 < 256) ? (Ws0 + (size_t)k0 * 256) : (Wn0 + (size_t)(k0 - 256) * 256);
    else
        W = (k0 < 256) ? (Ws1 + (size_t)k0 * 256) : (Wn1 + (size_t)(k0 - 256) * 256);
    unsigned short* Bt = which ? B1t : B0t;
    #pragma unroll
    for (int i = 0; i < 4; ++i) {
        int s  = t + i * 256;
        int kr = s >> 4;
        int c4 = s & 15;
        float4 v = *reinterpret_cast<const float4*>(W + (size_t)kr * 256 + n0 + c4 * 4);
        Ts[c4 * 4 + 0][kr] = f2bf(v.x);
        Ts[c4 * 4 + 1][kr] = f2bf(v.y);
        Ts[c4 * 4 + 2][kr] = f2bf(v.z);
        Ts[c4 * 4 + 3][kr] = f2bf(v.w);
    }
    __syncthreads();
    #pragma unroll
    for (int i = 0; i < 2; ++i) {
        int s  = t + i * 256;
        int nl = s >> 3;
        int k8 = (s & 7) * 8;
        *reinterpret_cast<short8*>(Bt + (size_t)(n0 + nl) * 512 + k0 + k8) =
            *reinterpret_cast<const short8*>(&Ts[nl][k8]);
    }
}

// ---------------- kernel 2: fused gather + neighbor-mean + bf16 MFMA GEMM ----------------
// 704 blocks x 512 threads; block owns 8 rows x 256 cols (M padded to 16 with
// zeroed LDS rows). ONE row per wave -> 5632 fully-parallel burst gathers
// (compile-time-unrolled fan: 25 loads in flight). Grid 2.75 blocks/CU cuts
// the round-5 2:1 per-CU tail to 3:2. GEMM: barrier-free K-loop, A frags from
// LDS, B frags from B0t (L2-resident). H0/H1 bf16.
__global__ __launch_bounds__(512) void k_gg0(
    const float* __restrict__ feat, const int* __restrict__ adj,
    const int* __restrict__ batch, const unsigned short* __restrict__ B0t,
    unsigned short* __restrict__ H0, unsigned short* __restrict__ H1) {
    __shared__ __align__(16) unsigned short As[16][520];
    const int t   = threadIdx.x;
    const int wv  = t >> 6;      // 0..7
    const int l   = t & 63;
    const int q   = l >> 4;
    const int m15 = l & 15;
    const int r0  = blockIdx.x * 8;
    const bool isBatch = (r0 < NBATCH);

    // zero pad rows 8..15 (one short8 per thread covers 8 rows x 64 slots)
    {
        int r = 8 + (t >> 6), c8 = (t & 63) * 8;
        *reinterpret_cast<short8*>(&As[r][c8]) = (short8)0;
    }

    // ---- Phase 1: one row per wave, burst-issued loads ----
    {
        const int r = wv;
        const int R = r0 + r;
        int node;
        if (isBatch) {
            node = batch[R];
        } else {
            int idx = R - NBATCH;
            int b   = idx / FAN1;
            int j   = idx - b * FAN1;
            node = adj[(size_t)batch[b] * FAN2 + j];
        }
        float4 selfv = *reinterpret_cast<const float4*>(
            feat + (size_t)node * FEATD + l * 4);
        const int* arow = adj + (size_t)node * FAN2;
        int myidx = (l < FAN2) ? arow[l] : 0;
        float4 acc = make_float4(0.f, 0.f, 0.f, 0.f);
        float s;
        if (isBatch) {
            #pragma unroll
            for (int k = 0; k < FAN1; ++k) {
                int nb = __shfl(myidx, k);
                float4 v = *reinterpret_cast<const float4*>(
                    feat + (size_t)nb * FEATD + l * 4);
                acc.x += v.x; acc.y += v.y; acc.z += v.z; acc.w += v.w;
            }
            s = 1.0f / (float)FAN1;
        } else {
            #pragma unroll
            for (int k = 0; k < FAN2; ++k) {
                int nb = __shfl(myidx, k);
                float4 v = *reinterpret_cast<const float4*>(
                    feat + (size_t)nb * FEATD + l * 4);
                acc.x += v.x; acc.y += v.y; acc.z += v.z; acc.w += v.w;
            }
            s = 1.0f / (float)FAN2;
        }
        acc.x *= s; acc.y *= s; acc.z *= s; acc.w *= s;
        ushort4 ps, pn;
        ps.x = f2bf(selfv.x); ps.y = f2bf(selfv.y);
        ps.z = f2bf(selfv.z); ps.w = f2bf(selfv.w);
        pn.x = f2bf(acc.x);   pn.y = f2bf(acc.y);
        pn.z = f2bf(acc.z);   pn.w = f2bf(acc.w);
        *reinterpret_cast<ushort4*>(&As[r][l * 4])       = ps;
        *reinterpret_cast<ushort4*>(&As[r][256 + l * 4]) = pn;
    }
    __syncthreads();

    // ---- Phase 2: barrier-free MFMA K-loop, B from global (L2) ----
    f32x4 acc0 = (f32x4)0.f, acc1 = (f32x4)0.f;
    const unsigned short* b0p = B0t + (size_t)(wv * 32 + m15) * 512;
    const unsigned short* b1p = B0t + (size_t)(wv * 32 + 16 + m15) * 512;
    #pragma unroll
    for (int kt = 0; kt < 8; ++kt) {
        const int kb = kt * 64;
        #pragma unroll
        for (int s2 = 0; s2 < 2; ++s2) {
            const int kk = kb + s2 * 32 + q * 8;
            short8 a  = *reinterpret_cast<const short8*>(&As[m15][kk]);
            short8 b0 = *reinterpret_cast<const short8*>(b0p + kk);
            short8 b1 = *reinterpret_cast<const short8*>(b1p + kk);
            acc0 = __builtin_amdgcn_mfma_f32_16x16x32_bf16(a, b0, acc0, 0, 0, 0);
            acc1 = __builtin_amdgcn_mfma_f32_16x16x32_bf16(a, b1, acc1, 0, 0, 0);
        }
    }

    // ---- Epilogue: relu + bf16 write (only M rows 0..7 are real) ----
    if (q < 2) {
        #pragma unroll
        for (int f = 0; f < 2; ++f) {
            const int n = wv * 32 + f * 16 + m15;
            const f32x4& a = f ? acc1 : acc0;
            #pragma unroll
            for (int j = 0; j < 4; ++j) {
                int m = r0 + q * 4 + j;
                unsigned short v = f2bf(fmaxf(a[j], 0.f));
                if (isBatch)
                    H0[(size_t)m * HIDD + n] = v;
                else
                    H1[(size_t)(m - NBATCH) * HIDD + n] = v;
            }
        }
    }
}

// ---------------- kernel 3: layer-1 bf16 MFMA + H1 mean + L2 norm ----------------
__global__ __launch_bounds__(512) void k_l1(
    const unsigned short* __restrict__ H0, const unsigned short* __restrict__ H1,
    const unsigned short* __restrict__ B1t, float* __restrict__ out) {
    __shared__ __align__(16) unsigned short As[16][520];
    __shared__ float rn[16][8];
    const int t   = threadIdx.x;
    const int wv  = t >> 6;      // 0..7
    const int l   = t & 63;
    const int q   = l >> 4;
    const int m15 = l & 15;
    const int rb  = blockIdx.x * 16;

    {   // stage H0 half
        int r = t >> 5, c8 = (t & 31) * 8;
        *reinterpret_cast<short8*>(&As[r][c8]) =
            *reinterpret_cast<const short8*>(H0 + (size_t)(rb + r) * HIDD + c8);
    }
    {   // stage mean(H1) half (fp32 accumulate)
        int r = t >> 5, c8 = (t & 31) * 8;
        const unsigned short* base = H1 + (size_t)(rb + r) * FAN1 * HIDD + c8;
        float a[8];
        #pragma unroll
        for (int e = 0; e < 8; ++e) a[e] = 0.f;
        #pragma unroll
        for (int j = 0; j < FAN1; ++j) {
            short8 v = *reinterpret_cast<const short8*>(base + (size_t)j * HIDD);
            #pragma unroll
            for (int e = 0; e < 8; ++e) a[e] += bf2f((unsigned short)v[e]);
        }
        short8 p;
        #pragma unroll
        for (int e = 0; e < 8; ++e) p[e] = (short)f2bf(a[e] * (1.0f / FAN1));
        *reinterpret_cast<short8*>(&As[r][256 + c8]) = p;
    }
    __syncthreads();

    f32x4 acc0 = (f32x4)0.f, acc1 = (f32x4)0.f;
    const unsigned short* b0p = B1t + (size_t)(wv * 32 + m15) * 512;
    const unsigned short* b1p = B1t + (size_t)(wv * 32 + 16 + m15) * 512;
    #pragma unroll
    for (int kt = 0; kt < 8; ++kt) {
        const int kb = kt * 64;
        #pragma unroll
        for (int s2 = 0; s2 < 2; ++s2) {
            const int kk = kb + s2 * 32 + q * 8;
            short8 a  = *reinterpret_cast<const short8*>(&As[m15][kk]);
            short8 b0 = *reinterpret_cast<const short8*>(b0p + kk);
            short8 b1 = *reinterpret_cast<const short8*>(b1p + kk);
            acc0 = __builtin_amdgcn_mfma_f32_16x16x32_bf16(a, b0, acc0, 0, 0, 0);
            acc1 = __builtin_amdgcn_mfma_f32_16x16x32_bf16(a, b1, acc1, 0, 0, 0);
        }
    }

    #pragma unroll
    for (int j = 0; j < 4; ++j) {
        float p = acc0[j] * acc0[j] + acc1[j] * acc1[j];
        p += __shfl_xor(p, 1);
        p += __shfl_xor(p, 2);
        p += __shfl_xor(p, 4);
        p += __shfl_xor(p, 8);
        if (m15 == 0) rn[q * 4 + j][wv] = p;
    }
    __syncthreads();

    #pragma unroll
    for (int j = 0; j < 4; ++j) {
        const int m = q * 4 + j;
        float s = rn[m][0] + rn[m][1] + rn[m][2] + rn[m][3]
                + rn[m][4] + rn[m][5] + rn[m][6] + rn[m][7];
        float inv = 1.0f / fmaxf(sqrtf(s), 1e-12f);
        out[(size_t)(rb + m) * HIDD + wv * 32 + m15]      = acc0[j] * inv;
        out[(size_t)(rb + m) * HIDD + wv * 32 + 16 + m15] = acc1[j] * inv;
    }
}

extern "C" void kernel_launch(void* const* d_in, const int* in_sizes, int n_in,
                              void* d_out, int out_size, void* d_ws, size_t ws_size,
                              hipStream_t stream) {
    const float* feat  = (const float*)d_in[0];
    const int*   adj   = (const int*)d_in[1];
    const int*   batch = (const int*)d_in[2];
    const float* Ws0   = (const float*)d_in[3];
    const float* Wn0   = (const float*)d_in[4];
    const float* Ws1   = (const float*)d_in[5];
    const float* Wn1   = (const float*)d_in[6];
    float* out = (float*)d_out;

    char* ws = (char*)d_ws;
    unsigned short* B0t = (unsigned short*)(ws + 0);        // 262,144 B
    unsigned short* B1t = (unsigned short*)(ws + 262144);   // 262,144 B
    unsigned short* H0  = (unsigned short*)(ws + 524288);   // 262,144 B
    unsigned short* H1  = (unsigned short*)(ws + 786432);   // 2,621,440 B

    k_wcvt<<<64, 256, 0, stream>>>(Ws0, Wn0, Ws1, Wn1, B0t, B1t);
    k_gg0<<<MTOT / 8, 512, 0, stream>>>(feat, adj, batch, B0t, H0, H1);
    k_l1<<<NBATCH / 16, 512, 0, stream>>>(H0, H1, B1t, out);
}

// Round 7
// 192.874 us; speedup vs baseline: 1.0092x; 1.0092x over previous
//
#include <hip/hip_runtime.h>
#include <cstdint>
#include <cstddef>

#define NNODES 100000
#define FEATD  256
#define HIDD   256
#define NBATCH 512
#define FAN1   10            // hop-1 fanout
#define FAN2   25            // hop-2 fanout
#define NS1    (NBATCH*FAN1) // 5120
#define MTOT   (NBATCH+NS1)  // 5632

typedef __attribute__((ext_vector_type(8))) short short8;
typedef __attribute__((ext_vector_type(4))) float f32x4;

__device__ __forceinline__ unsigned short f2bf(float f) {
    unsigned int u = __float_as_uint(f);
    unsigned int r = (u + 0x7fffu + ((u >> 16) & 1u)) >> 16;
    return (unsigned short)r;
}
__device__ __forceinline__ float bf2f(unsigned short h) {
    return __uint_as_float(((unsigned int)h) << 16);
}

// async 16B/lane global->LDS DMA: lane l reads g + l*16, lands at l + l*16.
// Zero VGPRs for the payload -> MLP no longer VGPR-pool-bound.
__device__ __forceinline__ void async_row16(const float* g, float* l) {
    __builtin_amdgcn_global_load_lds(
        (const __attribute__((address_space(1))) void*)g,
        (__attribute__((address_space(3))) void*)l, 16, 0, 0);
}
// s_waitcnt vmcnt(0) (expcnt/lgkmcnt masked off): 0x0f70
__device__ __forceinline__ void wait_vm0() { __builtin_amdgcn_s_waitcnt(0x0f70); }

// ---------------- kernel 1: W convert + transpose (both layers) ----------------
__global__ __launch_bounds__(256) void k_wcvt(
    const float* __restrict__ Ws0, const float* __restrict__ Wn0,
    const float* __restrict__ Ws1, const float* __restrict__ Wn1,
    unsigned short* __restrict__ B0t, unsigned short* __restrict__ B1t) {
    __shared__ unsigned short Ts[64][72];
    const int t     = threadIdx.x;
    const int which = blockIdx.x >> 5;
    const int loc   = blockIdx.x & 31;
    const int kt = loc >> 2, nt = loc & 3;
    const int k0 = kt * 64, n0 = nt * 64;
    const float* W;
    if (which == 0)
        W = (k0 < 256) ? (Ws0 + (size_t)k0 * 256) : (Wn0 + (size_t)(k0 - 256) * 256);
    else
        W = (k0 < 256) ? (Ws1 + (size_t)k0 * 256) : (Wn1 + (size_t)(k0 - 256) * 256);
    unsigned short* Bt = which ? B1t : B0t;
    #pragma unroll
    for (int i = 0; i < 4; ++i) {
        int s  = t + i * 256;
        int kr = s >> 4;
        int c4 = s & 15;
        float4 v = *reinterpret_cast<const float4*>(W + (size_t)kr * 256 + n0 + c4 * 4);
        Ts[c4 * 4 + 0][kr] = f2bf(v.x);
        Ts[c4 * 4 + 1][kr] = f2bf(v.y);
        Ts[c4 * 4 + 2][kr] = f2bf(v.z);
        Ts[c4 * 4 + 3][kr] = f2bf(v.w);
    }
    __syncthreads();
    #pragma unroll
    for (int i = 0; i < 2; ++i) {
        int s  = t + i * 256;
        int nl = s >> 3;
        int k8 = (s & 7) * 8;
        *reinterpret_cast<short8*>(Bt + (size_t)(n0 + nl) * 512 + k0 + k8) =
            *reinterpret_cast<const short8*>(&Ts[nl][k8]);
    }
}

// ---------------- kernel 2: fused gather + neighbor-mean + bf16 MFMA GEMM ----------------
// Round-5 tiling (352 blocks x 512 thr, 16 rows/block, 2 rows/wave, barrier-free
// GEMM with B from L2) but the neighbor gather now streams rows via
// global_load_lds into 5 per-wave LDS slots (chunks of 5 rows, vmcnt(0) drain,
// LDS accumulate). LDS 57.6KB -> 2 blocks/CU -> all 352 blocks co-resident.
__global__ __launch_bounds__(512) void k_gg0(
    const float* __restrict__ feat, const int* __restrict__ adj,
    const int* __restrict__ batch, const unsigned short* __restrict__ B0t,
    unsigned short* __restrict__ H0, unsigned short* __restrict__ H1) {
    __shared__ __align__(16) unsigned short As[16][520];
    __shared__ __align__(16) float Gs[8][5][256];   // per-wave DMA scratch
    const int t   = threadIdx.x;
    const int wv  = t >> 6;      // 0..7
    const int l   = t & 63;
    const int q   = l >> 4;
    const int m15 = l & 15;
    const int r0  = blockIdx.x * 16;
    const bool isBatch = (r0 < NBATCH);

    // ---- Phase 1: gather 2 rows per wave via LDS DMA chunks ----
    for (int i = 0; i < 2; ++i) {
        const int r = wv * 2 + i;
        const int R = r0 + r;
        int node;
        if (isBatch) {
            node = batch[R];
        } else {
            int idx = R - NBATCH;
            int b   = idx / FAN1;
            int j   = idx - b * FAN1;
            node = adj[(size_t)batch[b] * FAN2 + j];
        }
        float4 selfv = *reinterpret_cast<const float4*>(
            feat + (size_t)node * FEATD + l * 4);
        const int* arow = adj + (size_t)node * FAN2;
        int myidx = (l < FAN2) ? arow[l] : 0;
        float ax = 0.f, ay = 0.f, az = 0.f, aw = 0.f;
        const int nchunk = isBatch ? 2 : 5;   // fan 10 -> 2x5, fan 25 -> 5x5
        for (int ch = 0; ch < nchunk; ++ch) {
            #pragma unroll
            for (int c = 0; c < 5; ++c) {
                int nb = __shfl(myidx, ch * 5 + c);
                async_row16(feat + (size_t)nb * FEATD + l * 4, &Gs[wv][c][0]);
            }
            wait_vm0();
            #pragma unroll
            for (int c = 0; c < 5; ++c) {
                float4 v = *reinterpret_cast<const float4*>(&Gs[wv][c][l * 4]);
                ax += v.x; ay += v.y; az += v.z; aw += v.w;
            }
        }
        const float s = isBatch ? (1.0f / (float)FAN1) : (1.0f / (float)FAN2);
        ax *= s; ay *= s; az *= s; aw *= s;
        ushort4 ps, pn;
        ps.x = f2bf(selfv.x); ps.y = f2bf(selfv.y);
        ps.z = f2bf(selfv.z); ps.w = f2bf(selfv.w);
        pn.x = f2bf(ax);      pn.y = f2bf(ay);
        pn.z = f2bf(az);      pn.w = f2bf(aw);
        *reinterpret_cast<ushort4*>(&As[r][l * 4])       = ps;
        *reinterpret_cast<ushort4*>(&As[r][256 + l * 4]) = pn;
    }
    __syncthreads();

    // ---- Phase 2: barrier-free MFMA K-loop, B from global (L2) ----
    f32x4 acc0 = (f32x4)0.f, acc1 = (f32x4)0.f;
    const unsigned short* b0p = B0t + (size_t)(wv * 32 + m15) * 512;
    const unsigned short* b1p = B0t + (size_t)(wv * 32 + 16 + m15) * 512;
    #pragma unroll
    for (int kt = 0; kt < 8; ++kt) {
        const int kb = kt * 64;
        #pragma unroll
        for (int s2 = 0; s2 < 2; ++s2) {
            const int kk = kb + s2 * 32 + q * 8;
            short8 a  = *reinterpret_cast<const short8*>(&As[m15][kk]);
            short8 b0 = *reinterpret_cast<const short8*>(b0p + kk);
            short8 b1 = *reinterpret_cast<const short8*>(b1p + kk);
            acc0 = __builtin_amdgcn_mfma_f32_16x16x32_bf16(a, b0, acc0, 0, 0, 0);
            acc1 = __builtin_amdgcn_mfma_f32_16x16x32_bf16(a, b1, acc1, 0, 0, 0);
        }
    }

    // ---- Epilogue: relu + bf16 write ----
    #pragma unroll
    for (int f = 0; f < 2; ++f) {
        const int n = wv * 32 + f * 16 + m15;
        const f32x4& a = f ? acc1 : acc0;
        #pragma unroll
        for (int j = 0; j < 4; ++j) {
            int m = r0 + q * 4 + j;
            unsigned short v = f2bf(fmaxf(a[j], 0.f));
            if (isBatch)
                H0[(size_t)m * HIDD + n] = v;
            else
                H1[(size_t)(m - NBATCH) * HIDD + n] = v;
        }
    }
}

// ---------------- kernel 3: layer-1 bf16 MFMA + H1 mean + L2 norm ----------------
__global__ __launch_bounds__(512) void k_l1(
    const unsigned short* __restrict__ H0, const unsigned short* __restrict__ H1,
    const unsigned short* __restrict__ B1t, float* __restrict__ out) {
    __shared__ __align__(16) unsigned short As[16][520];
    __shared__ float rn[16][8];
    const int t   = threadIdx.x;
    const int wv  = t >> 6;      // 0..7
    const int l   = t & 63;
    const int q   = l >> 4;
    const int m15 = l & 15;
    const int rb  = blockIdx.x * 16;

    {   // stage H0 half
        int r = t >> 5, c8 = (t & 31) * 8;
        *reinterpret_cast<short8*>(&As[r][c8]) =
            *reinterpret_cast<const short8*>(H0 + (size_t)(rb + r) * HIDD + c8);
    }
    {   // stage mean(H1) half (fp32 accumulate)
        int r = t >> 5, c8 = (t & 31) * 8;
        const unsigned short* base = H1 + (size_t)(rb + r) * FAN1 * HIDD + c8;
        float a[8];
        #pragma unroll
        for (int e = 0; e < 8; ++e) a[e] = 0.f;
        #pragma unroll
        for (int j = 0; j < FAN1; ++j) {
            short8 v = *reinterpret_cast<const short8*>(base + (size_t)j * HIDD);
            #pragma unroll
            for (int e = 0; e < 8; ++e) a[e] += bf2f((unsigned short)v[e]);
        }
        short8 p;
        #pragma unroll
        for (int e = 0; e < 8; ++e) p[e] = (short)f2bf(a[e] * (1.0f / FAN1));
        *reinterpret_cast<short8*>(&As[r][256 + c8]) = p;
    }
    __syncthreads();

    f32x4 acc0 = (f32x4)0.f, acc1 = (f32x4)0.f;
    const unsigned short* b0p = B1t + (size_t)(wv * 32 + m15) * 512;
    const unsigned short* b1p = B1t + (size_t)(wv * 32 + 16 + m15) * 512;
    #pragma unroll
    for (int kt = 0; kt < 8; ++kt) {
        const int kb = kt * 64;
        #pragma unroll
        for (int s2 = 0; s2 < 2; ++s2) {
            const int kk = kb + s2 * 32 + q * 8;
            short8 a  = *reinterpret_cast<const short8*>(&As[m15][kk]);
            short8 b0 = *reinterpret_cast<const short8*>(b0p + kk);
            short8 b1 = *reinterpret_cast<const short8*>(b1p + kk);
            acc0 = __builtin_amdgcn_mfma_f32_16x16x32_bf16(a, b0, acc0, 0, 0, 0);
            acc1 = __builtin_amdgcn_mfma_f32_16x16x32_bf16(a, b1, acc1, 0, 0, 0);
        }
    }

    #pragma unroll
    for (int j = 0; j < 4; ++j) {
        float p = acc0[j] * acc0[j] + acc1[j] * acc1[j];
        p += __shfl_xor(p, 1);
        p += __shfl_xor(p, 2);
        p += __shfl_xor(p, 4);
        p += __shfl_xor(p, 8);
        if (m15 == 0) rn[q * 4 + j][wv] = p;
    }
    __syncthreads();

    #pragma unroll
    for (int j = 0; j < 4; ++j) {
        const int m = q * 4 + j;
        float s = rn[m][0] + rn[m][1] + rn[m][2] + rn[m][3]
                + rn[m][4] + rn[m][5] + rn[m][6] + rn[m][7];
        float inv = 1.0f / fmaxf(sqrtf(s), 1e-12f);
        out[(size_t)(rb + m) * HIDD + wv * 32 + m15]      = acc0[j] * inv;
        out[(size_t)(rb + m) * HIDD + wv * 32 + 16 + m15] = acc1[j] * inv;
    }
}

extern "C" void kernel_launch(void* const* d_in, const int* in_sizes, int n_in,
                              void* d_out, int out_size, void* d_ws, size_t ws_size,
                              hipStream_t stream) {
    const float* feat  = (const float*)d_in[0];
    const int*   adj   = (const int*)d_in[1];
    const int*   batch = (const int*)d_in[2];
    const float* Ws0   = (const float*)d_in[3];
    const float* Wn0   = (const float*)d_in[4];
    const float* Ws1   = (const float*)d_in[5];
    const float* Wn1   = (const float*)d_in[6];
    float* out = (float*)d_out;

    char* ws = (char*)d_ws;
    unsigned short* B0t = (unsigned short*)(ws + 0);        // 262,144 B
    unsigned short* B1t = (unsigned short*)(ws + 262144);   // 262,144 B
    unsigned short* H0  = (unsigned short*)(ws + 524288);   // 262,144 B
    unsigned short* H1  = (unsigned short*)(ws + 786432);   // 2,621,440 B

    k_wcvt<<<64, 256, 0, stream>>>(Ws0, Wn0, Ws1, Wn1, B0t, B1t);
    k_gg0<<<MTOT / 16, 512, 0, stream>>>(feat, adj, batch, B0t, H0, H1);
    k_l1<<<NBATCH / 16, 512, 0, stream>>>(H0, H1, B1t, out);
}